// Round 1
// baseline (2489.626 us; speedup 1.0000x reference)
//
#include <hip/hip_runtime.h>

#define N_NODES 50000
#define N_EDGES 800000
#define D 64

// ---------------------------------------------------------------------------
// deg[i] = number of incoming edges (as float)
__global__ __launch_bounds__(256) void deg_kernel(const int* __restrict__ dst,
                                                  float* __restrict__ deg) {
    int e = blockIdx.x * 256 + threadIdx.x;
    if (e < N_EDGES) atomicAdd(&deg[dst[e]], 1.0f);
}

// ---------------------------------------------------------------------------
// abc[n,192] = h[n,64] @ [W1|W2|W3] + [b1|0|b3]
// 64-row tile per block, 256 threads, each thread computes 4 rows x 12 cols.
// h tile stored with rotation swizzle (k+r)&63: conflict-free staging writes
// and compute reads with zero padding (fits exactly 64KB total LDS).
__global__ __launch_bounds__(256) void gemm3_kernel(
    const float* __restrict__ h,
    const float* __restrict__ W1, const float* __restrict__ b1,
    const float* __restrict__ W2,
    const float* __restrict__ W3, const float* __restrict__ b3,
    float* __restrict__ abc, int n)
{
    __shared__ float sh[64][64];    // 16 KB, swizzled
    __shared__ float sw[64][192];   // 48 KB: [k][ W1 | W2 | W3 ]
    const int t = threadIdx.x;
    const int row0 = blockIdx.x * 64;

    // load weights (coalesced, 16 iters)
    for (int i = t; i < 64 * 64; i += 256) {
        int k = i >> 6, j = i & 63;
        sw[k][j]       = W1[i];
        sw[k][j + 64]  = W2[i];
        sw[k][j + 128] = W3[i];
    }
    // load h tile, coalesced global reads, swizzled LDS writes
    for (int i = t; i < 64 * 64; i += 256) {
        int r = i >> 6, k = i & 63;
        int gr = row0 + r;
        float v = (gr < n) ? h[gr * 64 + k] : 0.0f;
        sh[r][(k + r) & 63] = v;
    }
    __syncthreads();

    const int tr = t >> 4;   // 0..15
    const int tc = t & 15;   // 0..15
    float acc[4][12];
    #pragma unroll
    for (int r = 0; r < 4; ++r)
        #pragma unroll
        for (int c = 0; c < 12; ++c) acc[r][c] = 0.0f;

    #pragma unroll 4
    for (int k = 0; k < 64; ++k) {
        float av[4];
        #pragma unroll
        for (int r = 0; r < 4; ++r) {
            int row = tr * 4 + r;
            av[r] = sh[row][(k + row) & 63];
        }
        // 12 consecutive cols, 48B-aligned -> 3x float4
        const float4* wp = (const float4*)&sw[k][tc * 12];
        float4 w0 = wp[0], w1 = wp[1], w2 = wp[2];
        float wv[12] = {w0.x, w0.y, w0.z, w0.w,
                        w1.x, w1.y, w1.z, w1.w,
                        w2.x, w2.y, w2.z, w2.w};
        #pragma unroll
        for (int r = 0; r < 4; ++r)
            #pragma unroll
            for (int c = 0; c < 12; ++c)
                acc[r][c] += av[r] * wv[c];
    }

    #pragma unroll
    for (int r = 0; r < 4; ++r) {
        int gr = row0 + tr * 4 + r;
        if (gr >= n) continue;
        #pragma unroll
        for (int c = 0; c < 12; ++c) {
            int j = tc * 12 + c;
            float v = acc[r][c];
            if (j < 64)        v += b1[j];
            else if (j >= 128) v += b3[j - 128];
            abc[(long)gr * 192 + j] = v;
        }
    }
}

// ---------------------------------------------------------------------------
// S[dst] += a_row[src], a = abc cols [0,64). One thread per (edge, 4-feature).
__global__ __launch_bounds__(256) void scatter_kernel(
    const int* __restrict__ src, const int* __restrict__ dst,
    const float* __restrict__ abc, float* __restrict__ S)
{
    long gid = (long)blockIdx.x * 256 + threadIdx.x;
    int e = (int)(gid >> 4);
    int q = (int)(gid & 15);
    if (e >= N_EDGES) return;
    int s = src[e], d = dst[e];
    const float4 v = *(const float4*)(abc + (long)s * 192 + q * 4);
    float* out = S + (long)d * 64 + q * 4;
    atomicAdd(out + 0, v.x);
    atomicAdd(out + 1, v.y);
    atomicAdd(out + 2, v.z);
    atomicAdd(out + 3, v.w);
}

// ---------------------------------------------------------------------------
// out = relu( (S - deg*b + c) @ Wl + bl ),  b = abc cols [64,128), c = [128,192)
__global__ __launch_bounds__(256) void combine_gemm_kernel(
    const float* __restrict__ S, const float* __restrict__ abc,
    const float* __restrict__ deg,
    const float* __restrict__ Wl, const float* __restrict__ bl,
    float* __restrict__ out, int n)
{
    __shared__ float sp[64][65];   // padded, conflict-free
    __shared__ float sw[64][64];
    const int t = threadIdx.x;
    const int row0 = blockIdx.x * 64;

    for (int i = t; i < 64 * 64; i += 256) sw[i >> 6][i & 63] = Wl[i];
    for (int i = t; i < 64 * 64; i += 256) {
        int r = i >> 6, k = i & 63;
        int gr = row0 + r;
        float v = 0.0f;
        if (gr < n) {
            float dg = deg[gr];
            v = S[(long)gr * 64 + k]
              - dg * abc[(long)gr * 192 + 64 + k]
              +      abc[(long)gr * 192 + 128 + k];
        }
        sp[r][k] = v;
    }
    __syncthreads();

    const int tr = t >> 4;
    const int tc = t & 15;
    float acc[4][4];
    #pragma unroll
    for (int r = 0; r < 4; ++r)
        #pragma unroll
        for (int c = 0; c < 4; ++c) acc[r][c] = 0.0f;

    #pragma unroll 4
    for (int k = 0; k < 64; ++k) {
        float av[4];
        #pragma unroll
        for (int r = 0; r < 4; ++r) av[r] = sp[tr * 4 + r][k];
        float4 wv = *(const float4*)&sw[k][tc * 4];
        float w[4] = {wv.x, wv.y, wv.z, wv.w};
        #pragma unroll
        for (int r = 0; r < 4; ++r)
            #pragma unroll
            for (int c = 0; c < 4; ++c)
                acc[r][c] += av[r] * w[c];
    }

    #pragma unroll
    for (int r = 0; r < 4; ++r) {
        int gr = row0 + tr * 4 + r;
        if (gr >= n) continue;
        #pragma unroll
        for (int c = 0; c < 4; ++c) {
            int j = tc * 4 + c;
            float v = acc[r][c] + bl[j];
            out[(long)gr * 64 + j] = fmaxf(v, 0.0f);
        }
    }
}

// ---------------------------------------------------------------------------
extern "C" void kernel_launch(void* const* d_in, const int* in_sizes, int n_in,
                              void* d_out, int out_size, void* d_ws, size_t ws_size,
                              hipStream_t stream) {
    const float* x  = (const float*)d_in[0];
    const int*   ei = (const int*)d_in[1];
    const int*   src = ei;
    const int*   dst = ei + N_EDGES;

    float* ws  = (float*)d_ws;
    float* deg = ws;                         // N_NODES
    float* abc = ws + 51200;                 // N_NODES * 192
    float* S   = abc + (long)N_NODES * 192;  // N_NODES * 64
    float* h1  = S   + (long)N_NODES * 64;   // N_NODES * 64

    const int NBLK = (N_NODES + 63) / 64;    // 782

    hipMemsetAsync(deg, 0, N_NODES * sizeof(float), stream);
    deg_kernel<<<(N_EDGES + 255) / 256, 256, 0, stream>>>(dst, deg);

    const float* hin = x;
    for (int l = 0; l < 3; ++l) {
        int base = 2 + l * 7;
        const float* W1 = (const float*)d_in[base + 0];
        const float* b1 = (const float*)d_in[base + 1];
        const float* W2 = (const float*)d_in[base + 2];
        const float* W3 = (const float*)d_in[base + 3];
        const float* b3 = (const float*)d_in[base + 4];
        const float* Wl = (const float*)d_in[base + 5];
        const float* bl = (const float*)d_in[base + 6];

        gemm3_kernel<<<NBLK, 256, 0, stream>>>(hin, W1, b1, W2, W3, b3, abc, N_NODES);

        hipMemsetAsync(S, 0, (size_t)N_NODES * 64 * sizeof(float), stream);
        scatter_kernel<<<(N_EDGES * 16 + 255) / 256, 256, 0, stream>>>(src, dst, abc, S);

        float* outp = (l == 2) ? (float*)d_out : h1;
        combine_gemm_kernel<<<NBLK, 256, 0, stream>>>(S, abc, deg, Wl, bl, outp, N_NODES);
        hin = h1;
    }
}

// Round 2
// 731.540 us; speedup vs baseline: 3.4033x; 3.4033x over previous
//
#include <hip/hip_runtime.h>

#define N_NODES 50000
#define N_EDGES 800000
#define D 64
#define SCAN_T 1024

// ---------------------------------------------------------------------------
// cnt[i] = number of incoming edges (int histogram)
__global__ __launch_bounds__(256) void hist_kernel(const int* __restrict__ dst,
                                                   int* __restrict__ cnt) {
    int e = blockIdx.x * 256 + threadIdx.x;
    if (e < N_EDGES) atomicAdd(&cnt[dst[e]], 1);
}

// ---------------------------------------------------------------------------
// Exclusive scan of cnt -> off[0..N], and reset cnt to off values (cursor).
// Single block of 1024 threads; 49 elements/thread.
__global__ __launch_bounds__(SCAN_T) void scan_kernel(int* __restrict__ cnt,
                                                      int* __restrict__ off) {
    __shared__ int part[SCAN_T];
    const int t = threadIdx.x;
    const int CH = (N_NODES + SCAN_T - 1) / SCAN_T;  // 49
    int beg = t * CH, end = min(beg + CH, N_NODES);
    int s = 0;
    for (int i = beg; i < end; ++i) s += cnt[i];
    part[t] = s;
    __syncthreads();
    for (int d = 1; d < SCAN_T; d <<= 1) {
        int v = (t >= d) ? part[t - d] : 0;
        __syncthreads();
        part[t] += v;
        __syncthreads();
    }
    int run = (t == 0) ? 0 : part[t - 1];
    for (int i = beg; i < end; ++i) {
        int c = cnt[i];
        off[i] = run;
        cnt[i] = run;   // becomes the fill cursor
        run += c;
    }
    if (t == SCAN_T - 1) off[N_NODES] = run;
}

// ---------------------------------------------------------------------------
// csr[cursor[dst[e]]++] = src[e]
__global__ __launch_bounds__(256) void fill_kernel(const int* __restrict__ src,
                                                   const int* __restrict__ dst,
                                                   int* __restrict__ cursor,
                                                   int* __restrict__ csr) {
    int e = blockIdx.x * 256 + threadIdx.x;
    if (e < N_EDGES) {
        int pos = atomicAdd(&cursor[dst[e]], 1);
        csr[pos] = src[e];
    }
}

// ---------------------------------------------------------------------------
// abc[n,192] = h[n,64] @ [W1|W2|W3] + [b1|0|b3]
__global__ __launch_bounds__(256) void gemm3_kernel(
    const float* __restrict__ h,
    const float* __restrict__ W1, const float* __restrict__ b1,
    const float* __restrict__ W2,
    const float* __restrict__ W3, const float* __restrict__ b3,
    float* __restrict__ abc, int n)
{
    __shared__ float sh[64][64];    // 16 KB, rotation-swizzled
    __shared__ float sw[64][192];   // 48 KB: [k][ W1 | W2 | W3 ]
    const int t = threadIdx.x;
    const int row0 = blockIdx.x * 64;

    for (int i = t; i < 64 * 64; i += 256) {
        int k = i >> 6, j = i & 63;
        sw[k][j]       = W1[i];
        sw[k][j + 64]  = W2[i];
        sw[k][j + 128] = W3[i];
    }
    for (int i = t; i < 64 * 64; i += 256) {
        int r = i >> 6, k = i & 63;
        int gr = row0 + r;
        float v = (gr < n) ? h[gr * 64 + k] : 0.0f;
        sh[r][(k + r) & 63] = v;
    }
    __syncthreads();

    const int tr = t >> 4;   // 0..15
    const int tc = t & 15;   // 0..15
    float acc[4][12];
    #pragma unroll
    for (int r = 0; r < 4; ++r)
        #pragma unroll
        for (int c = 0; c < 12; ++c) acc[r][c] = 0.0f;

    #pragma unroll 4
    for (int k = 0; k < 64; ++k) {
        float av[4];
        #pragma unroll
        for (int r = 0; r < 4; ++r) {
            int row = tr * 4 + r;
            av[r] = sh[row][(k + row) & 63];
        }
        const float4* wp = (const float4*)&sw[k][tc * 12];
        float4 w0 = wp[0], w1 = wp[1], w2 = wp[2];
        float wv[12] = {w0.x, w0.y, w0.z, w0.w,
                        w1.x, w1.y, w1.z, w1.w,
                        w2.x, w2.y, w2.z, w2.w};
        #pragma unroll
        for (int r = 0; r < 4; ++r)
            #pragma unroll
            for (int c = 0; c < 12; ++c)
                acc[r][c] += av[r] * wv[c];
    }

    #pragma unroll
    for (int r = 0; r < 4; ++r) {
        int gr = row0 + tr * 4 + r;
        if (gr >= n) continue;
        #pragma unroll
        for (int c = 0; c < 12; ++c) {
            int j = tc * 12 + c;
            float v = acc[r][c];
            if (j < 64)        v += b1[j];
            else if (j >= 128) v += b3[j - 128];
            abc[(long)gr * 192 + j] = v;
        }
    }
}

// ---------------------------------------------------------------------------
// CSR gather: S[i,:] = sum_{j in in(i)} a[csr[j], :].  One wave per node,
// 64 lanes = 64 features; each edge reads a coalesced 256B row of `a`.
__global__ __launch_bounds__(256) void gather_kernel(
    const int* __restrict__ off, const int* __restrict__ csr,
    const float* __restrict__ abc, float* __restrict__ S, int n)
{
    int node = blockIdx.x * 4 + (threadIdx.x >> 6);
    int lane = threadIdx.x & 63;
    if (node >= n) return;
    int beg = off[node], end = off[node + 1];
    float acc = 0.0f;
    int j = beg;
    for (; j + 1 < end; j += 2) {
        int s0 = csr[j], s1 = csr[j + 1];
        float v0 = abc[(long)s0 * 192 + lane];
        float v1 = abc[(long)s1 * 192 + lane];
        acc += v0;
        acc += v1;
    }
    if (j < end) acc += abc[(long)csr[j] * 192 + lane];
    S[(long)node * 64 + lane] = acc;
}

// ---------------------------------------------------------------------------
// out = relu( (S - deg*b + c) @ Wl + bl ); deg from CSR offsets.
__global__ __launch_bounds__(256) void combine_gemm_kernel(
    const float* __restrict__ S, const float* __restrict__ abc,
    const int* __restrict__ off,
    const float* __restrict__ Wl, const float* __restrict__ bl,
    float* __restrict__ out, int n)
{
    __shared__ float sp[64][65];
    __shared__ float sw[64][64];
    const int t = threadIdx.x;
    const int row0 = blockIdx.x * 64;

    for (int i = t; i < 64 * 64; i += 256) sw[i >> 6][i & 63] = Wl[i];
    for (int i = t; i < 64 * 64; i += 256) {
        int r = i >> 6, k = i & 63;
        int gr = row0 + r;
        float v = 0.0f;
        if (gr < n) {
            float dg = (float)(off[gr + 1] - off[gr]);
            v = S[(long)gr * 64 + k]
              - dg * abc[(long)gr * 192 + 64 + k]
              +      abc[(long)gr * 192 + 128 + k];
        }
        sp[r][k] = v;
    }
    __syncthreads();

    const int tr = t >> 4;
    const int tc = t & 15;
    float acc[4][4];
    #pragma unroll
    for (int r = 0; r < 4; ++r)
        #pragma unroll
        for (int c = 0; c < 4; ++c) acc[r][c] = 0.0f;

    #pragma unroll 4
    for (int k = 0; k < 64; ++k) {
        float av[4];
        #pragma unroll
        for (int r = 0; r < 4; ++r) av[r] = sp[tr * 4 + r][k];
        float4 wv = *(const float4*)&sw[k][tc * 4];
        float w[4] = {wv.x, wv.y, wv.z, wv.w};
        #pragma unroll
        for (int r = 0; r < 4; ++r)
            #pragma unroll
            for (int c = 0; c < 4; ++c)
                acc[r][c] += av[r] * w[c];
    }

    #pragma unroll
    for (int r = 0; r < 4; ++r) {
        int gr = row0 + tr * 4 + r;
        if (gr >= n) continue;
        #pragma unroll
        for (int c = 0; c < 4; ++c) {
            int j = tc * 4 + c;
            float v = acc[r][c] + bl[j];
            out[(long)gr * 64 + j] = fmaxf(v, 0.0f);
        }
    }
}

// ---------------------------------------------------------------------------
extern "C" void kernel_launch(void* const* d_in, const int* in_sizes, int n_in,
                              void* d_out, int out_size, void* d_ws, size_t ws_size,
                              hipStream_t stream) {
    const float* x  = (const float*)d_in[0];
    const int*   ei = (const int*)d_in[1];
    const int*   src = ei;
    const int*   dst = ei + N_EDGES;

    char* wsb = (char*)d_ws;
    int*   cnt = (int*)wsb;                                  // N_NODES (then cursor)
    int*   off = cnt + N_NODES;                              // N_NODES + 1
    int*   csr = off + N_NODES + 1;                          // N_EDGES
    float* abc = (float*)(csr + N_EDGES);                    // N_NODES * 192
    float* S   = abc + (long)N_NODES * 192;                  // N_NODES * 64
    float* h1  = S   + (long)N_NODES * 64;                   // N_NODES * 64

    const int NBLK = (N_NODES + 63) / 64;    // 782

    // ---- CSR build (per call; ws is re-poisoned) ----
    hipMemsetAsync(cnt, 0, N_NODES * sizeof(int), stream);
    hist_kernel<<<(N_EDGES + 255) / 256, 256, 0, stream>>>(dst, cnt);
    scan_kernel<<<1, SCAN_T, 0, stream>>>(cnt, off);
    fill_kernel<<<(N_EDGES + 255) / 256, 256, 0, stream>>>(src, dst, cnt, csr);

    const float* hin = x;
    for (int l = 0; l < 3; ++l) {
        int base = 2 + l * 7;
        const float* W1 = (const float*)d_in[base + 0];
        const float* b1 = (const float*)d_in[base + 1];
        const float* W2 = (const float*)d_in[base + 2];
        const float* W3 = (const float*)d_in[base + 3];
        const float* b3 = (const float*)d_in[base + 4];
        const float* Wl = (const float*)d_in[base + 5];
        const float* bl = (const float*)d_in[base + 6];

        gemm3_kernel<<<NBLK, 256, 0, stream>>>(hin, W1, b1, W2, W3, b3, abc, N_NODES);

        gather_kernel<<<(N_NODES + 3) / 4, 256, 0, stream>>>(off, csr, abc, S, N_NODES);

        float* outp = (l == 2) ? (float*)d_out : h1;
        combine_gemm_kernel<<<NBLK, 256, 0, stream>>>(S, abc, off, Wl, bl, outp, N_NODES);
        hin = h1;
    }
}

// Round 3
// 599.597 us; speedup vs baseline: 4.1522x; 1.2201x over previous
//
#include <hip/hip_runtime.h>

#define N_NODES 50000
#define N_EDGES 800000
#define D 64
#define SCAN_NB ((N_NODES + 255) / 256)   // 196

// ---------------------------------------------------------------------------
// cnt[i] = number of incoming edges (int histogram)
__global__ __launch_bounds__(256) void hist_kernel(const int* __restrict__ dst,
                                                   int* __restrict__ cnt) {
    int e = blockIdx.x * 256 + threadIdx.x;
    if (e < N_EDGES) atomicAdd(&cnt[dst[e]], 1);
}

// ---------------------------------------------------------------------------
// Pass A: per-block exclusive prescan of cnt into off; block sums into bsum.
__global__ __launch_bounds__(256) void scanA_kernel(const int* __restrict__ cnt,
                                                    int* __restrict__ off,
                                                    int* __restrict__ bsum) {
    __shared__ int tmp[256];
    const int t = threadIdx.x;
    const int i = blockIdx.x * 256 + t;
    int v = (i < N_NODES) ? cnt[i] : 0;
    tmp[t] = v;
    __syncthreads();
    #pragma unroll
    for (int d = 1; d < 256; d <<= 1) {
        int u = (t >= d) ? tmp[t - d] : 0;
        __syncthreads();
        tmp[t] += u;
        __syncthreads();
    }
    if (i < N_NODES) off[i] = tmp[t] - v;           // exclusive
    if (t == 255) bsum[blockIdx.x] = tmp[255];
}

// ---------------------------------------------------------------------------
// Pass B: single block scans the SCAN_NB block sums; writes off[N_NODES].
__global__ __launch_bounds__(256) void scanB_kernel(const int* __restrict__ bsum,
                                                    int* __restrict__ boff,
                                                    int* __restrict__ off) {
    __shared__ int tmp[256];
    const int t = threadIdx.x;
    int v = (t < SCAN_NB) ? bsum[t] : 0;
    tmp[t] = v;
    __syncthreads();
    #pragma unroll
    for (int d = 1; d < 256; d <<= 1) {
        int u = (t >= d) ? tmp[t - d] : 0;
        __syncthreads();
        tmp[t] += u;
        __syncthreads();
    }
    if (t < SCAN_NB) boff[t] = tmp[t] - v;
    if (t == 255) off[N_NODES] = tmp[255];
}

// ---------------------------------------------------------------------------
// Pass C: off[i] += boff[block]; cursor[i] = off[i].
__global__ __launch_bounds__(256) void scanC_kernel(const int* __restrict__ boff,
                                                    int* __restrict__ off,
                                                    int* __restrict__ cursor) {
    int i = blockIdx.x * 256 + threadIdx.x;
    if (i < N_NODES) {
        int o = off[i] + boff[blockIdx.x];
        off[i] = o;
        cursor[i] = o;
    }
}

// ---------------------------------------------------------------------------
// csr[cursor[dst[e]]++] = src[e]
__global__ __launch_bounds__(256) void fill_kernel(const int* __restrict__ src,
                                                   const int* __restrict__ dst,
                                                   int* __restrict__ cursor,
                                                   int* __restrict__ csr) {
    int e = blockIdx.x * 256 + threadIdx.x;
    if (e < N_EDGES) {
        int pos = atomicAdd(&cursor[dst[e]], 1);
        csr[pos] = src[e];
    }
}

// ---------------------------------------------------------------------------
// abc[n,192] = h[n,64] @ [W1|W2|W3] + [b1|0|b3]
__global__ __launch_bounds__(256) void gemm3_kernel(
    const float* __restrict__ h,
    const float* __restrict__ W1, const float* __restrict__ b1,
    const float* __restrict__ W2,
    const float* __restrict__ W3, const float* __restrict__ b3,
    float* __restrict__ abc, int n)
{
    __shared__ float sh[64][64];    // 16 KB, rotation-swizzled
    __shared__ float sw[64][192];   // 48 KB: [k][ W1 | W2 | W3 ]
    const int t = threadIdx.x;
    const int row0 = blockIdx.x * 64;

    for (int i = t; i < 64 * 64; i += 256) {
        int k = i >> 6, j = i & 63;
        sw[k][j]       = W1[i];
        sw[k][j + 64]  = W2[i];
        sw[k][j + 128] = W3[i];
    }
    for (int i = t; i < 64 * 64; i += 256) {
        int r = i >> 6, k = i & 63;
        int gr = row0 + r;
        float v = (gr < n) ? h[gr * 64 + k] : 0.0f;
        sh[r][(k + r) & 63] = v;
    }
    __syncthreads();

    const int tr = t >> 4;   // 0..15
    const int tc = t & 15;   // 0..15
    float acc[4][12];
    #pragma unroll
    for (int r = 0; r < 4; ++r)
        #pragma unroll
        for (int c = 0; c < 12; ++c) acc[r][c] = 0.0f;

    #pragma unroll 4
    for (int k = 0; k < 64; ++k) {
        float av[4];
        #pragma unroll
        for (int r = 0; r < 4; ++r) {
            int row = tr * 4 + r;
            av[r] = sh[row][(k + row) & 63];
        }
        const float4* wp = (const float4*)&sw[k][tc * 12];
        float4 w0 = wp[0], w1 = wp[1], w2 = wp[2];
        float wv[12] = {w0.x, w0.y, w0.z, w0.w,
                        w1.x, w1.y, w1.z, w1.w,
                        w2.x, w2.y, w2.z, w2.w};
        #pragma unroll
        for (int r = 0; r < 4; ++r)
            #pragma unroll
            for (int c = 0; c < 12; ++c)
                acc[r][c] += av[r] * wv[c];
    }

    #pragma unroll
    for (int r = 0; r < 4; ++r) {
        int gr = row0 + tr * 4 + r;
        if (gr >= n) continue;
        #pragma unroll
        for (int c = 0; c < 12; ++c) {
            int j = tc * 12 + c;
            float v = acc[r][c];
            if (j < 64)        v += b1[j];
            else if (j >= 128) v += b3[j - 128];
            abc[(long)gr * 192 + j] = v;
        }
    }
}

// ---------------------------------------------------------------------------
// CSR gather: S[i,:] = sum_{j in in(i)} a[csr[j], :].  One wave per node,
// 64 lanes = 64 features; each edge reads a coalesced 256B row of `a`.
// Unrolled x4 for memory-level parallelism.
__global__ __launch_bounds__(256) void gather_kernel(
    const int* __restrict__ off, const int* __restrict__ csr,
    const float* __restrict__ abc, float* __restrict__ S, int n)
{
    int node = blockIdx.x * 4 + (threadIdx.x >> 6);
    int lane = threadIdx.x & 63;
    if (node >= n) return;
    int beg = off[node], end = off[node + 1];
    float acc = 0.0f;
    int j = beg;
    for (; j + 3 < end; j += 4) {
        int s0 = csr[j], s1 = csr[j + 1], s2 = csr[j + 2], s3 = csr[j + 3];
        float v0 = abc[(long)s0 * 192 + lane];
        float v1 = abc[(long)s1 * 192 + lane];
        float v2 = abc[(long)s2 * 192 + lane];
        float v3 = abc[(long)s3 * 192 + lane];
        acc += v0 + v1 + v2 + v3;
    }
    for (; j < end; ++j) acc += abc[(long)csr[j] * 192 + lane];
    S[(long)node * 64 + lane] = acc;
}

// ---------------------------------------------------------------------------
// out = relu( (S - deg*b + c) @ Wl + bl ); deg from CSR offsets.
__global__ __launch_bounds__(256) void combine_gemm_kernel(
    const float* __restrict__ S, const float* __restrict__ abc,
    const int* __restrict__ off,
    const float* __restrict__ Wl, const float* __restrict__ bl,
    float* __restrict__ out, int n)
{
    __shared__ float sp[64][65];
    __shared__ float sw[64][64];
    const int t = threadIdx.x;
    const int row0 = blockIdx.x * 64;

    for (int i = t; i < 64 * 64; i += 256) sw[i >> 6][i & 63] = Wl[i];
    for (int i = t; i < 64 * 64; i += 256) {
        int r = i >> 6, k = i & 63;
        int gr = row0 + r;
        float v = 0.0f;
        if (gr < n) {
            float dg = (float)(off[gr + 1] - off[gr]);
            v = S[(long)gr * 64 + k]
              - dg * abc[(long)gr * 192 + 64 + k]
              +      abc[(long)gr * 192 + 128 + k];
        }
        sp[r][k] = v;
    }
    __syncthreads();

    const int tr = t >> 4;
    const int tc = t & 15;
    float acc[4][4];
    #pragma unroll
    for (int r = 0; r < 4; ++r)
        #pragma unroll
        for (int c = 0; c < 4; ++c) acc[r][c] = 0.0f;

    #pragma unroll 4
    for (int k = 0; k < 64; ++k) {
        float av[4];
        #pragma unroll
        for (int r = 0; r < 4; ++r) av[r] = sp[tr * 4 + r][k];
        float4 wv = *(const float4*)&sw[k][tc * 4];
        float w[4] = {wv.x, wv.y, wv.z, wv.w};
        #pragma unroll
        for (int r = 0; r < 4; ++r)
            #pragma unroll
            for (int c = 0; c < 4; ++c)
                acc[r][c] += av[r] * w[c];
    }

    #pragma unroll
    for (int r = 0; r < 4; ++r) {
        int gr = row0 + tr * 4 + r;
        if (gr >= n) continue;
        #pragma unroll
        for (int c = 0; c < 4; ++c) {
            int j = tc * 4 + c;
            float v = acc[r][c] + bl[j];
            out[(long)gr * 64 + j] = fmaxf(v, 0.0f);
        }
    }
}

// ---------------------------------------------------------------------------
extern "C" void kernel_launch(void* const* d_in, const int* in_sizes, int n_in,
                              void* d_out, int out_size, void* d_ws, size_t ws_size,
                              hipStream_t stream) {
    const float* x  = (const float*)d_in[0];
    const int*   ei = (const int*)d_in[1];
    const int*   src = ei;
    const int*   dst = ei + N_EDGES;

    char* wsb = (char*)d_ws;
    int*   cnt  = (int*)wsb;                                 // N_NODES (then cursor)
    int*   off  = cnt + N_NODES;                             // N_NODES + 1
    int*   bsum = off + N_NODES + 1;                         // SCAN_NB
    int*   boff = bsum + SCAN_NB;                            // SCAN_NB
    int*   csr  = boff + SCAN_NB;                            // N_EDGES
    float* abc  = (float*)(csr + N_EDGES);                   // N_NODES * 192
    float* S    = abc + (long)N_NODES * 192;                 // N_NODES * 64
    float* h1   = S   + (long)N_NODES * 64;                  // N_NODES * 64

    const int NBLK = (N_NODES + 63) / 64;    // 782

    // ---- CSR build (per call; ws is re-poisoned) ----
    hipMemsetAsync(cnt, 0, N_NODES * sizeof(int), stream);
    hist_kernel<<<(N_EDGES + 255) / 256, 256, 0, stream>>>(dst, cnt);
    scanA_kernel<<<SCAN_NB, 256, 0, stream>>>(cnt, off, bsum);
    scanB_kernel<<<1, 256, 0, stream>>>(bsum, boff, off);
    scanC_kernel<<<SCAN_NB, 256, 0, stream>>>(boff, off, cnt);
    fill_kernel<<<(N_EDGES + 255) / 256, 256, 0, stream>>>(src, dst, cnt, csr);

    const float* hin = x;
    for (int l = 0; l < 3; ++l) {
        int base = 2 + l * 7;
        const float* W1 = (const float*)d_in[base + 0];
        const float* b1 = (const float*)d_in[base + 1];
        const float* W2 = (const float*)d_in[base + 2];
        const float* W3 = (const float*)d_in[base + 3];
        const float* b3 = (const float*)d_in[base + 4];
        const float* Wl = (const float*)d_in[base + 5];
        const float* bl = (const float*)d_in[base + 6];

        gemm3_kernel<<<NBLK, 256, 0, stream>>>(hin, W1, b1, W2, W3, b3, abc, N_NODES);

        gather_kernel<<<(N_NODES + 3) / 4, 256, 0, stream>>>(off, csr, abc, S, N_NODES);

        float* outp = (l == 2) ? (float*)d_out : h1;
        combine_gemm_kernel<<<NBLK, 256, 0, stream>>>(S, abc, off, Wl, bl, outp, N_NODES);
        hin = h1;
    }
}

// Round 4
// 401.110 us; speedup vs baseline: 6.2068x; 1.4948x over previous
//
#include <hip/hip_runtime.h>

#define N_NODES 50000
#define N_EDGES 800000
#define SCAN_NB ((N_NODES + 255) / 256)   // 196

typedef __attribute__((ext_vector_type(8))) short short8;
typedef __attribute__((ext_vector_type(4))) float f32x4;

__device__ inline unsigned short f2b(float f) {
    union { float f; unsigned u; } c; c.f = f;
    return (unsigned short)((c.u + 0x7FFFu + ((c.u >> 16) & 1u)) >> 16);
}
__device__ inline float b2f(unsigned short h) {
    union { unsigned u; float f; } c; c.u = ((unsigned)h) << 16;
    return c.f;
}

// ---------------------------------------------------------------------------
// CSR build (unchanged from round 3)
__global__ __launch_bounds__(256) void hist_kernel(const int* __restrict__ dst,
                                                   int* __restrict__ cnt) {
    int e = blockIdx.x * 256 + threadIdx.x;
    if (e < N_EDGES) atomicAdd(&cnt[dst[e]], 1);
}

__global__ __launch_bounds__(256) void scanA_kernel(const int* __restrict__ cnt,
                                                    int* __restrict__ off,
                                                    int* __restrict__ bsum) {
    __shared__ int tmp[256];
    const int t = threadIdx.x;
    const int i = blockIdx.x * 256 + t;
    int v = (i < N_NODES) ? cnt[i] : 0;
    tmp[t] = v;
    __syncthreads();
    #pragma unroll
    for (int d = 1; d < 256; d <<= 1) {
        int u = (t >= d) ? tmp[t - d] : 0;
        __syncthreads();
        tmp[t] += u;
        __syncthreads();
    }
    if (i < N_NODES) off[i] = tmp[t] - v;
    if (t == 255) bsum[blockIdx.x] = tmp[255];
}

__global__ __launch_bounds__(256) void scanB_kernel(const int* __restrict__ bsum,
                                                    int* __restrict__ boff,
                                                    int* __restrict__ off) {
    __shared__ int tmp[256];
    const int t = threadIdx.x;
    int v = (t < SCAN_NB) ? bsum[t] : 0;
    tmp[t] = v;
    __syncthreads();
    #pragma unroll
    for (int d = 1; d < 256; d <<= 1) {
        int u = (t >= d) ? tmp[t - d] : 0;
        __syncthreads();
        tmp[t] += u;
        __syncthreads();
    }
    if (t < SCAN_NB) boff[t] = tmp[t] - v;
    if (t == 255) off[N_NODES] = tmp[255];
}

__global__ __launch_bounds__(256) void scanC_kernel(const int* __restrict__ boff,
                                                    int* __restrict__ off,
                                                    int* __restrict__ cursor) {
    int i = blockIdx.x * 256 + threadIdx.x;
    if (i < N_NODES) {
        int o = off[i] + boff[blockIdx.x];
        off[i] = o;
        cursor[i] = o;
    }
}

__global__ __launch_bounds__(256) void fill_kernel(const int* __restrict__ src,
                                                   const int* __restrict__ dst,
                                                   int* __restrict__ cursor,
                                                   int* __restrict__ csr) {
    int e = blockIdx.x * 256 + threadIdx.x;
    if (e < N_EDGES) {
        int pos = atomicAdd(&cursor[dst[e]], 1);
        csr[pos] = src[e];
    }
}

// ---------------------------------------------------------------------------
// x (fp32) -> bf16
__global__ __launch_bounds__(256) void convert_x_kernel(const float* __restrict__ x,
                                                        unsigned short* __restrict__ xb) {
    long i = ((long)blockIdx.x * 256 + threadIdx.x) * 4;
    if (i < (long)N_NODES * 64) {
        float4 v = *(const float4*)(x + i);
        ushort4 o;
        o.x = f2b(v.x); o.y = f2b(v.y); o.z = f2b(v.z); o.w = f2b(v.w);
        *(ushort4*)(xb + i) = o;
    }
}

// ---------------------------------------------------------------------------
// Pack one layer's weights into B-fragment order (bf16):
// Wp[ct][s][lane][j], ct 0..11 = [W1|W2|W3] col-tiles, ct 12..15 = Wl tiles.
// frag element: B[k = s*32 + (lane>>4)*8 + j][col = ct*16 + (lane&15)]
__global__ __launch_bounds__(256) void pack_w_kernel(
    const float* __restrict__ W1, const float* __restrict__ W2,
    const float* __restrict__ W3, const float* __restrict__ Wl,
    unsigned short* __restrict__ Wp)
{
    for (int idx = threadIdx.x; idx < 16 * 2 * 64 * 8; idx += 256) {
        int j = idx & 7, lane = (idx >> 3) & 63, s = (idx >> 9) & 1, ct = idx >> 10;
        int k = s * 32 + (lane >> 4) * 8 + j;
        int col = ct * 16 + (lane & 15);
        float v;
        if (ct < 4)       v = W1[k * 64 + col];
        else if (ct < 8)  v = W2[k * 64 + col - 64];
        else if (ct < 12) v = W3[k * 64 + col - 128];
        else              v = Wl[k * 64 + col - 192];
        Wp[idx] = f2b(v);
    }
}

// ---------------------------------------------------------------------------
// [a|b|c] = h @ [W1|W2|W3] + [b1|0|b3], bf16 MFMA, no LDS.
// Block = 4 waves = 64 rows; wave = 16 rows x 192 cols (12 col-tiles).
__global__ __launch_bounds__(256) void gemm3_mfma_kernel(
    const unsigned short* __restrict__ hbf,
    const unsigned short* __restrict__ Wp,
    const float* __restrict__ b1, const float* __restrict__ b3,
    unsigned short* __restrict__ abf, unsigned short* __restrict__ bbf,
    unsigned short* __restrict__ cbf, int n)
{
    const int t = threadIdx.x;
    const int lane = t & 63;
    const int quad = lane >> 4, lm = lane & 15;
    const int row_base = blockIdx.x * 64 + (t >> 6) * 16;

    int arow = min(row_base + lm, n - 1);
    const unsigned short* hrow = hbf + (long)arow * 64;
    short8 a0 = *(const short8*)(hrow + quad * 8);        // k in [0,32)
    short8 a1 = *(const short8*)(hrow + 32 + quad * 8);   // k in [32,64)

    const short8* wp = (const short8*)Wp;
    f32x4 acc[12];
    #pragma unroll
    for (int ct = 0; ct < 12; ++ct) {
        f32x4 z = {0.f, 0.f, 0.f, 0.f};
        short8 w0 = wp[(ct * 2 + 0) * 64 + lane];
        short8 w1 = wp[(ct * 2 + 1) * 64 + lane];
        z = __builtin_amdgcn_mfma_f32_16x16x32_bf16(a0, w0, z, 0, 0, 0);
        z = __builtin_amdgcn_mfma_f32_16x16x32_bf16(a1, w1, z, 0, 0, 0);
        acc[ct] = z;
    }

    // Epilogue: D row = quad*4 + reg, col = ct*16 + lm
    #pragma unroll
    for (int ct = 0; ct < 12; ++ct) {
        int col = ct * 16 + lm;
        float bias = 0.f;
        unsigned short* dstp;
        int lcol;
        if (ct < 4)       { bias = b1[col];        dstp = abf; lcol = col; }
        else if (ct < 8)  {                        dstp = bbf; lcol = col - 64; }
        else              { bias = b3[col - 128];  dstp = cbf; lcol = col - 128; }
        #pragma unroll
        for (int r = 0; r < 4; ++r) {
            int g = row_base + quad * 4 + r;
            if (g < n) dstp[(long)g * 64 + lcol] = f2b(acc[ct][r] + bias);
        }
    }
}

// ---------------------------------------------------------------------------
// CSR gather over bf16 a-rows: S[i,:] = sum a[csr[j],:]. One wave per node.
__global__ __launch_bounds__(256) void gather_kernel(
    const int* __restrict__ off, const int* __restrict__ csr,
    const unsigned short* __restrict__ abf, float* __restrict__ S, int n)
{
    int node = blockIdx.x * 4 + (threadIdx.x >> 6);
    int lane = threadIdx.x & 63;
    if (node >= n) return;
    int beg = off[node], end = off[node + 1];
    float acc = 0.0f;
    int j = beg;
    for (; j + 3 < end; j += 4) {
        int s0 = csr[j], s1 = csr[j + 1], s2 = csr[j + 2], s3 = csr[j + 3];
        float v0 = b2f(abf[(long)s0 * 64 + lane]);
        float v1 = b2f(abf[(long)s1 * 64 + lane]);
        float v2 = b2f(abf[(long)s2 * 64 + lane]);
        float v3 = b2f(abf[(long)s3 * 64 + lane]);
        acc += v0 + v1 + v2 + v3;
    }
    for (; j < end; ++j) acc += b2f(abf[(long)csr[j] * 64 + lane]);
    S[(long)node * 64 + lane] = acc;
}

// ---------------------------------------------------------------------------
// out = relu( (S - deg*b + c) @ Wl + bl ), P built in A-fragment registers.
__global__ __launch_bounds__(256) void combine_mfma_kernel(
    const float* __restrict__ S, const unsigned short* __restrict__ bbf,
    const unsigned short* __restrict__ cbf, const int* __restrict__ off,
    const unsigned short* __restrict__ Wp, const float* __restrict__ bl,
    float* __restrict__ out_f, unsigned short* __restrict__ out_b,
    int n, int last)
{
    const int t = threadIdx.x;
    const int lane = t & 63;
    const int quad = lane >> 4, lm = lane & 15;
    const int row_base = blockIdx.x * 64 + (t >> 6) * 16;

    int prow = min(row_base + lm, n - 1);
    float deg = (float)(off[prow + 1] - off[prow]);

    short8 p[2];
    #pragma unroll
    for (int s = 0; s < 2; ++s) {
        int k0 = s * 32 + quad * 8;
        const float* sp = S + (long)prow * 64 + k0;
        float4 s0 = *(const float4*)sp;
        float4 s1 = *(const float4*)(sp + 4);
        const short8 bv = *(const short8*)(bbf + (long)prow * 64 + k0);
        const short8 cv = *(const short8*)(cbf + (long)prow * 64 + k0);
        float sv[8] = {s0.x, s0.y, s0.z, s0.w, s1.x, s1.y, s1.z, s1.w};
        short8 pv;
        #pragma unroll
        for (int j = 0; j < 8; ++j) {
            float v = sv[j] - deg * b2f((unsigned short)bv[j]) + b2f((unsigned short)cv[j]);
            pv[j] = (short)f2b(v);
        }
        p[s] = pv;
    }

    const short8* wp = (const short8*)Wp;
    #pragma unroll
    for (int ct = 0; ct < 4; ++ct) {
        f32x4 z = {0.f, 0.f, 0.f, 0.f};
        short8 w0 = wp[((12 + ct) * 2 + 0) * 64 + lane];
        short8 w1 = wp[((12 + ct) * 2 + 1) * 64 + lane];
        z = __builtin_amdgcn_mfma_f32_16x16x32_bf16(p[0], w0, z, 0, 0, 0);
        z = __builtin_amdgcn_mfma_f32_16x16x32_bf16(p[1], w1, z, 0, 0, 0);
        int col = ct * 16 + lm;
        float bias = bl[col];
        #pragma unroll
        for (int r = 0; r < 4; ++r) {
            int g = row_base + quad * 4 + r;
            if (g < n) {
                float v = fmaxf(z[r] + bias, 0.0f);
                if (last) out_f[(long)g * 64 + col] = v;
                else      out_b[(long)g * 64 + col] = f2b(v);
            }
        }
    }
}

// ---------------------------------------------------------------------------
extern "C" void kernel_launch(void* const* d_in, const int* in_sizes, int n_in,
                              void* d_out, int out_size, void* d_ws, size_t ws_size,
                              hipStream_t stream) {
    const float* x  = (const float*)d_in[0];
    const int*   ei = (const int*)d_in[1];
    const int*   src = ei;
    const int*   dst = ei + N_EDGES;

    char* wsb = (char*)d_ws;
    float*          S   = (float*)(wsb);                       // 12.8 MB
    unsigned short* abf = (unsigned short*)(wsb + 12800000);   // 6.4 MB
    unsigned short* bbf = (unsigned short*)(wsb + 19200000);   // 6.4 MB
    unsigned short* cbf = (unsigned short*)(wsb + 25600000);   // 6.4 MB
    unsigned short* h0  = (unsigned short*)(wsb + 32000000);   // 6.4 MB
    unsigned short* h1  = (unsigned short*)(wsb + 38400000);   // 6.4 MB
    unsigned short* Wp  = (unsigned short*)(wsb + 44800000);   // 3 * 32 KB
    int* cnt  = (int*)(wsb + 44900000);                        // N_NODES
    int* off  = cnt + N_NODES;                                 // N_NODES+1
    int* bsum = off + N_NODES + 1;
    int* boff = bsum + SCAN_NB;
    int* csr  = boff + SCAN_NB;                                // N_EDGES

    const int NBLK = (N_NODES + 63) / 64;    // 782

    // ---- CSR build ----
    hipMemsetAsync(cnt, 0, N_NODES * sizeof(int), stream);
    hist_kernel<<<(N_EDGES + 255) / 256, 256, 0, stream>>>(dst, cnt);
    scanA_kernel<<<SCAN_NB, 256, 0, stream>>>(cnt, off, bsum);
    scanB_kernel<<<1, 256, 0, stream>>>(bsum, boff, off);
    scanC_kernel<<<SCAN_NB, 256, 0, stream>>>(boff, off, cnt);
    fill_kernel<<<(N_EDGES + 255) / 256, 256, 0, stream>>>(src, dst, cnt, csr);

    // ---- bf16 conversions / weight packing ----
    convert_x_kernel<<<(N_NODES * 64 / 4 + 255) / 256, 256, 0, stream>>>(x, h0);
    for (int l = 0; l < 3; ++l) {
        int base = 2 + l * 7;
        pack_w_kernel<<<1, 256, 0, stream>>>(
            (const float*)d_in[base + 0], (const float*)d_in[base + 2],
            (const float*)d_in[base + 3], (const float*)d_in[base + 5],
            Wp + l * 16384);
    }

    const unsigned short* hin = h0;
    for (int l = 0; l < 3; ++l) {
        int base = 2 + l * 7;
        const float* b1 = (const float*)d_in[base + 1];
        const float* b3 = (const float*)d_in[base + 4];
        const float* bl = (const float*)d_in[base + 6];
        const unsigned short* wp = Wp + l * 16384;

        gemm3_mfma_kernel<<<NBLK, 256, 0, stream>>>(hin, wp, b1, b3,
                                                    abf, bbf, cbf, N_NODES);

        gather_kernel<<<(N_NODES + 3) / 4, 256, 0, stream>>>(off, csr, abf, S, N_NODES);

        int last = (l == 2);
        combine_mfma_kernel<<<NBLK, 256, 0, stream>>>(
            S, bbf, cbf, off, wp, bl,
            (float*)d_out, h1, N_NODES, last);
        hin = h1;
    }
}